// Round 2
// baseline (1707.317 us; speedup 1.0000x reference)
//
#include <hip/hip_runtime.h>

// Sinkhorn normalization, N=8192, fp32 in/out.
// Multiplicative-space formulation with fp16 E = exp(s0):
//   v_i = 1 / sum_j E_ij u_j        (row step)
//   u_j = 1 / sum_i E_ij v_i        (col step)
//   out = exp(s0_ij) * v_i * u_j
//
// Row step + column partials fused into ONE pass over E per iteration.
// vs round 1 (which regressed): staging goes through LDS via async
// global_load_lds (double-buffered 2x64KB), NOT through registers.
// Round 1's register staging (e[8]+en[8] = 64 VGPRs of data) blew the
// 128-VGPR cap that __launch_bounds__(1024) imposes -> scratch spills
// -> HBM traffic doubled + latency. Now only 4 half8 fragments are live
// (~60 VGPRs), and counted s_waitcnt vmcnt(4) keeps the next batch's DMA
// in flight across all barriers so the memory pipe never drains.

constexpr int N = 8192;
constexpr int TB = 1024;                 // threads per fused block (16 waves)
constexpr int CHUNKS = 256;              // one block per CU
constexpr int CHUNK_ROWS = N / CHUNKS;   // 32
constexpr int NH8 = N / 8;               // half8 per row = 1024
constexpr int NV4 = N / 4;               // float4 per row = 2048

typedef _Float16 half8 __attribute__((ext_vector_type(8)));

// ---------------------------------------------------------------------------
// Kernel A: E = exp(s0) (fp16), v = 1/rowsum (u == 1 initially), and the
// iteration-0 column partials — one pass over s0. Thread t owns cols
// 8t..8t+7 (same ownership as fused_pass / col layout of part).
__global__ __launch_bounds__(TB) void convert_fused(const float* __restrict__ s0,
                                                    _Float16* __restrict__ E,
                                                    float* __restrict__ v,
                                                    float* __restrict__ part) {
    const int t = threadIdx.x;
    const int lane = t & 63, wave = t >> 6;
    const int row0 = blockIdx.x * CHUNK_ROWS;
    const float4* __restrict__ s4 = (const float4*)s0;
    half8* __restrict__ e8 = (half8*)E;
    __shared__ float red[2][16][4];      // double-buffered wave partials
    float acc[8] = {0.f, 0.f, 0.f, 0.f, 0.f, 0.f, 0.f, 0.f};
    for (int b = 0; b < CHUNK_ROWS; b += 4) {
        const int rb = (b >> 2) & 1;
        float ex[4][8], d[4];
        #pragma unroll
        for (int r = 0; r < 4; ++r) {
            const int row = row0 + b + r;
            const size_t ro = (size_t)row * NV4;
            float4 xa = s4[ro + 2 * t];
            float4 xb = s4[ro + 2 * t + 1];
            ex[r][0] = __expf(xa.x); ex[r][1] = __expf(xa.y);
            ex[r][2] = __expf(xa.z); ex[r][3] = __expf(xa.w);
            ex[r][4] = __expf(xb.x); ex[r][5] = __expf(xb.y);
            ex[r][6] = __expf(xb.z); ex[r][7] = __expf(xb.w);
            half8 h;
            #pragma unroll
            for (int k = 0; k < 8; ++k) h[k] = (_Float16)ex[r][k];
            e8[(size_t)row * NH8 + t] = h;
            d[r] = ((ex[r][0] + ex[r][1]) + (ex[r][2] + ex[r][3]))
                 + ((ex[r][4] + ex[r][5]) + (ex[r][6] + ex[r][7]));
        }
        #pragma unroll
        for (int off = 32; off > 0; off >>= 1) {
            #pragma unroll
            for (int r = 0; r < 4; ++r) d[r] += __shfl_down(d[r], off, 64);
        }
        if (lane == 0) {
            #pragma unroll
            for (int r = 0; r < 4; ++r) red[rb][wave][r] = d[r];
        }
        __syncthreads();
        // redundant cross-wave reduce: lane l reads red[rb][l>>2][l&3] (= float l)
        float pv = (&red[rb][0][0])[lane];
        pv += __shfl_xor(pv, 4, 64);
        pv += __shfl_xor(pv, 8, 64);
        pv += __shfl_xor(pv, 16, 64);
        pv += __shfl_xor(pv, 32, 64);
        const float inv = 1.f / pv;      // lane l holds 1/rowsum(row l&3)
        if (t < 4) v[row0 + b + t] = inv;
        const float vr[4] = {__shfl(inv, 0, 64), __shfl(inv, 1, 64),
                             __shfl(inv, 2, 64), __shfl(inv, 3, 64)};
        #pragma unroll
        for (int r = 0; r < 4; ++r) {
            #pragma unroll
            for (int k = 0; k < 8; ++k) acc[k] += vr[r] * ex[r][k];
        }
    }
    float4* __restrict__ p4 = (float4*)(part + (size_t)blockIdx.x * N);
    p4[2 * t]     = make_float4(acc[0], acc[1], acc[2], acc[3]);
    p4[2 * t + 1] = make_float4(acc[4], acc[5], acc[6], acc[7]);
}

// ---------------------------------------------------------------------------
// Kernel B: fused row step + column partials, one pass over E.
// LDS-staged batches of 4 rows (64KB), double-buffered; async DMA with
// counted vmcnt so loads stay in flight across every barrier.
__global__ __launch_bounds__(TB) void fused_pass(const _Float16* __restrict__ E,
                                                 const float* __restrict__ u,
                                                 float* __restrict__ v,
                                                 float* __restrict__ part) {
    const int t = threadIdx.x;
    const int lane = t & 63, wave = t >> 6;
    const int row0 = blockIdx.x * CHUNK_ROWS;
    __shared__ _Float16 buf[2][4][N];    // 2 x 64KB
    __shared__ float red[16][4];
    const float4* __restrict__ u4 = (const float4*)u;
    const float4 ua = u4[2 * t], ub = u4[2 * t + 1];
    float acc[8] = {0.f, 0.f, 0.f, 0.f, 0.f, 0.f, 0.f, 0.f};

    // async-stage batch `batch` (4 rows) into buf[p]; dest is linear in t,
    // so per-wave it is uniform-base + lane*16 as global_load_lds requires.
    auto stage = [&](int batch, int p) {
        #pragma unroll
        for (int r = 0; r < 4; ++r) {
            const _Float16* g = E + (size_t)(row0 + batch * 4 + r) * N + t * 8;
            __builtin_amdgcn_global_load_lds(
                (const __attribute__((address_space(1))) void*)g,
                (__attribute__((address_space(3))) void*)&buf[p][r][t * 8],
                16, 0, 0);
        }
    };
    stage(0, 0);
    stage(1, 1);
    #pragma unroll
    for (int b = 0; b < CHUNK_ROWS / 4; ++b) {       // 8 batches
        if (b < 7) { asm volatile("s_waitcnt vmcnt(4)" ::: "memory"); }
        else       { asm volatile("s_waitcnt vmcnt(0)" ::: "memory"); }
        __syncthreads();                             // batch b data ready (all waves)
        half8 e[4];
        #pragma unroll
        for (int r = 0; r < 4; ++r)
            e[r] = *(const half8*)&buf[b & 1][r][t * 8];
        float d[4];
        #pragma unroll
        for (int r = 0; r < 4; ++r)
            d[r] = ua.x * (float)e[r][0] + ua.y * (float)e[r][1]
                 + ua.z * (float)e[r][2] + ua.w * (float)e[r][3]
                 + ub.x * (float)e[r][4] + ub.y * (float)e[r][5]
                 + ub.z * (float)e[r][6] + ub.w * (float)e[r][7];
        #pragma unroll
        for (int off = 32; off > 0; off >>= 1) {
            #pragma unroll
            for (int r = 0; r < 4; ++r) d[r] += __shfl_down(d[r], off, 64);
        }
        if (lane == 0) {
            #pragma unroll
            for (int r = 0; r < 4; ++r) red[wave][r] = d[r];
        }
        __syncthreads();                             // red complete; buf[b&1] free
        if (b < 6) stage(b + 2, b & 1);              // refill freed buffer early
        float pv = (&red[0][0])[lane];               // lane l -> red[l>>2][l&3]
        pv += __shfl_xor(pv, 4, 64);
        pv += __shfl_xor(pv, 8, 64);
        pv += __shfl_xor(pv, 16, 64);
        pv += __shfl_xor(pv, 32, 64);
        const float inv = 1.f / pv;
        if (t < 4) v[row0 + b * 4 + t] = inv;
        const float vr[4] = {__shfl(inv, 0, 64), __shfl(inv, 1, 64),
                             __shfl(inv, 2, 64), __shfl(inv, 3, 64)};
        #pragma unroll
        for (int r = 0; r < 4; ++r) {
            #pragma unroll
            for (int k = 0; k < 8; ++k)
                acc[k] += vr[r] * (float)e[r][k];
        }
    }
    float4* __restrict__ p4 = (float4*)(part + (size_t)blockIdx.x * N);
    p4[2 * t]     = make_float4(acc[0], acc[1], acc[2], acc[3]);
    p4[2 * t + 1] = make_float4(acc[4], acc[5], acc[6], acc[7]);
}

// ---------------------------------------------------------------------------
// u[j] = 1 / sum_c part[c][j].  Grid = 256 blocks; each block 32 cols,
// 8-way split over the 256 chunks.
__global__ __launch_bounds__(256) void col_reduce(const float* __restrict__ part,
                                                  float* __restrict__ u) {
    const int c = threadIdx.x & 31;
    const int seg = threadIdx.x >> 5;            // 0..7
    const int col = blockIdx.x * 32 + c;
    float sum = 0.f;
    #pragma unroll 8
    for (int i = 0; i < CHUNKS / 8; ++i)
        sum += part[(size_t)(seg * (CHUNKS / 8) + i) * N + col];
    __shared__ float smem[8][32];
    smem[seg][c] = sum;
    __syncthreads();
    if (threadIdx.x < 32) {
        float s = 0.f;
        #pragma unroll
        for (int q = 0; q < 8; ++q) s += smem[q][threadIdx.x];
        u[blockIdx.x * 32 + threadIdx.x] = 1.f / s;
    }
}

// ---------------------------------------------------------------------------
// out = exp(s0_ij) * v_i * u_j  (fp32 path; overwrites E/part scratch in d_out)
__global__ __launch_bounds__(256) void final_out(const float* __restrict__ s0,
                                                 const float* __restrict__ v,
                                                 const float* __restrict__ u,
                                                 float* __restrict__ out) {
    const int row = blockIdx.x;
    const float vi = v[row];
    const float4* __restrict__ srow = (const float4*)(s0 + (size_t)row * N);
    const float4* __restrict__ u4 = (const float4*)u;
    float4* __restrict__ orow = (float4*)(out + (size_t)row * N);
    for (int k = threadIdx.x; k < NV4; k += 256) {
        float4 x = srow[k];
        float4 uu = u4[k];
        float4 r;
        r.x = __expf(x.x) * vi * uu.x;
        r.y = __expf(x.y) * vi * uu.y;
        r.z = __expf(x.z) * vi * uu.z;
        r.w = __expf(x.w) * vi * uu.w;
        orow[k] = r;
    }
}

extern "C" void kernel_launch(void* const* d_in, const int* in_sizes, int n_in,
                              void* d_out, int out_size, void* d_ws, size_t ws_size,
                              hipStream_t stream) {
    const float* s0 = (const float*)d_in[0];
    float* out = (float*)d_out;

    _Float16* E = (_Float16*)d_out;                              // 128 MB scratch
    float* part = (float*)((char*)d_out + (size_t)N * N * 2);    // 8 MB at +128 MB
    float* v = (float*)d_ws;                                     // 8192 floats
    float* u = v + N;                                            // 8192 floats

    convert_fused<<<CHUNKS, TB, 0, stream>>>(s0, E, v, part);    // row step #1 (u==1) + col partials
    col_reduce<<<N / 32, 256, 0, stream>>>(part, u);             // col step #1
    for (int it = 1; it < 10; ++it) {
        fused_pass<<<CHUNKS, TB, 0, stream>>>(E, u, v, part);    // row step + col partials
        col_reduce<<<N / 32, 256, 0, stream>>>(part, u);         // col step
    }
    final_out<<<N, 256, 0, stream>>>(s0, v, u, out);
}

// Round 3
// 766.161 us; speedup vs baseline: 2.2284x; 2.2284x over previous
//
#include <hip/hip_runtime.h>

// Sinkhorn normalization, N=8192, fp32 in/out.
// Multiplicative-space formulation with fp16 E = exp(s0):
//   v_i = 1 / sum_j E_ij u_j        (row step)
//   u_j = 1 / sum_i E_ij v_i        (col step)
//   out = exp(s0_ij) * v_i * u_j
//
// Row step + column partials fused into ONE pass over E per iteration.
// vs rounds 1/2 (both regressed): the hot loops use RAW s_barrier
// (__builtin_amdgcn_s_barrier) instead of __syncthreads. __syncthreads
// emits s_waitcnt vmcnt(0) lgkmcnt(0) before s_barrier, draining the
// whole memory pipe every 4-row batch -> issue/drain lockstep at ~0.9TB/s.
// With raw barriers + lgkmcnt(0) only (for the LDS reduce scratch), the
// E loads/stores stay in flight across every barrier (T3/T4 counted-vmcnt
// pattern). E has no cross-thread reuse, so staging is pure registers:
// e[4] current + en[4] prefetch = 32 VGPRs, safely under the 128-VGPR cap
// of 1024-thread blocks (round 1's 8+8 rows spilled).
// red[2] double-buffer makes ONE barrier per batch race-free: writers of
// batch b+2 are separated from readers of batch b by barrier b+1.

constexpr int N = 8192;
constexpr int TB = 1024;                 // threads per fused block (16 waves)
constexpr int CHUNKS = 256;              // one block per CU
constexpr int CHUNK_ROWS = N / CHUNKS;   // 32
constexpr int NH8 = N / 8;               // half8 per row = 1024
constexpr int NV4 = N / 4;               // float4 per row = 2048

typedef _Float16 half8 __attribute__((ext_vector_type(8)));

// ---------------------------------------------------------------------------
// Kernel A: E = exp(s0) (fp16), v = 1/rowsum (u == 1 initially), and the
// iteration-0 column partials — one pass over s0. Thread t owns cols 8t..8t+7.
__global__ __launch_bounds__(TB) void convert_fused(const float* __restrict__ s0,
                                                    _Float16* __restrict__ E,
                                                    float* __restrict__ v,
                                                    float* __restrict__ part) {
    const int t = threadIdx.x;
    const int lane = t & 63, wave = t >> 6;
    const int row0 = blockIdx.x * CHUNK_ROWS;
    const float4* __restrict__ s4 = (const float4*)s0;
    half8* __restrict__ e8 = (half8*)E;
    __shared__ float red[2][16][4];      // double-buffered wave partials
    float acc[8] = {0.f, 0.f, 0.f, 0.f, 0.f, 0.f, 0.f, 0.f};
    for (int b = 0; b < CHUNK_ROWS / 4; ++b) {
        const int rb = b & 1;
        float ex[4][8], d[4];
        #pragma unroll
        for (int r = 0; r < 4; ++r) {
            const int row = row0 + b * 4 + r;
            const size_t ro = (size_t)row * NV4;
            float4 xa = s4[ro + 2 * t];
            float4 xb = s4[ro + 2 * t + 1];
            ex[r][0] = __expf(xa.x); ex[r][1] = __expf(xa.y);
            ex[r][2] = __expf(xa.z); ex[r][3] = __expf(xa.w);
            ex[r][4] = __expf(xb.x); ex[r][5] = __expf(xb.y);
            ex[r][6] = __expf(xb.z); ex[r][7] = __expf(xb.w);
            half8 h;
            #pragma unroll
            for (int k = 0; k < 8; ++k) h[k] = (_Float16)ex[r][k];
            e8[(size_t)row * NH8 + t] = h;   // store stays in flight (no drain below)
            d[r] = ((ex[r][0] + ex[r][1]) + (ex[r][2] + ex[r][3]))
                 + ((ex[r][4] + ex[r][5]) + (ex[r][6] + ex[r][7]));
        }
        #pragma unroll
        for (int off = 32; off > 0; off >>= 1) {
            #pragma unroll
            for (int r = 0; r < 4; ++r) d[r] += __shfl_down(d[r], off, 64);
        }
        if (lane == 0) {
            #pragma unroll
            for (int r = 0; r < 4; ++r) red[rb][wave][r] = d[r];
        }
        asm volatile("s_waitcnt lgkmcnt(0)" ::: "memory");   // red write visible
        __builtin_amdgcn_sched_barrier(0);
        __builtin_amdgcn_s_barrier();                        // NO vmcnt drain
        // cross-wave reduce: lane l reads red[rb][l>>2][l&3] (= float l)
        float pv = (&red[rb][0][0])[lane];
        pv += __shfl_xor(pv, 4, 64);
        pv += __shfl_xor(pv, 8, 64);
        pv += __shfl_xor(pv, 16, 64);
        pv += __shfl_xor(pv, 32, 64);
        const float inv = 1.f / pv;      // lane l holds 1/rowsum(row l&3)
        if (t < 4) v[row0 + b * 4 + t] = inv;
        const float vr[4] = {__shfl(inv, 0, 64), __shfl(inv, 1, 64),
                             __shfl(inv, 2, 64), __shfl(inv, 3, 64)};
        #pragma unroll
        for (int r = 0; r < 4; ++r) {
            #pragma unroll
            for (int k = 0; k < 8; ++k) acc[k] += vr[r] * ex[r][k];
        }
    }
    float4* __restrict__ p4 = (float4*)(part + (size_t)blockIdx.x * N);
    p4[2 * t]     = make_float4(acc[0], acc[1], acc[2], acc[3]);
    p4[2 * t + 1] = make_float4(acc[4], acc[5], acc[6], acc[7]);
}

// ---------------------------------------------------------------------------
// Kernel B: fused row step + column partials, one pass over E.
// Register-staged 4-row batches with next-batch prefetch; raw s_barrier so
// the prefetch loads stay in flight across the per-batch reduction.
__global__ __launch_bounds__(TB) void fused_pass(const _Float16* __restrict__ E,
                                                 const float* __restrict__ u,
                                                 float* __restrict__ v,
                                                 float* __restrict__ part) {
    const int t = threadIdx.x;
    const int lane = t & 63, wave = t >> 6;
    const int row0 = blockIdx.x * CHUNK_ROWS;
    const half8* __restrict__ e8 = (const half8*)E;
    const float4* __restrict__ u4 = (const float4*)u;
    const float4 ua = u4[2 * t], ub = u4[2 * t + 1];
    __shared__ float red[2][16][4];      // double-buffered wave partials
    float acc[8] = {0.f, 0.f, 0.f, 0.f, 0.f, 0.f, 0.f, 0.f};
    half8 e[4];
    #pragma unroll
    for (int r = 0; r < 4; ++r)
        e[r] = e8[(size_t)(row0 + r) * NH8 + t];
    for (int b = 0; b < CHUNK_ROWS / 4; ++b) {       // 8 batches
        const int rb = b & 1;
        half8 en[4];
        if (b < CHUNK_ROWS / 4 - 1) {
            // issue next batch FIRST; compiler emits counted vmcnt(4) before
            // the e-use below -> one batch always in flight.
            #pragma unroll
            for (int r = 0; r < 4; ++r)
                en[r] = e8[(size_t)(row0 + (b + 1) * 4 + r) * NH8 + t];
        }
        float d[4];
        #pragma unroll
        for (int r = 0; r < 4; ++r)
            d[r] = ua.x * (float)e[r][0] + ua.y * (float)e[r][1]
                 + ua.z * (float)e[r][2] + ua.w * (float)e[r][3]
                 + ub.x * (float)e[r][4] + ub.y * (float)e[r][5]
                 + ub.z * (float)e[r][6] + ub.w * (float)e[r][7];
        #pragma unroll
        for (int off = 32; off > 0; off >>= 1) {
            #pragma unroll
            for (int r = 0; r < 4; ++r) d[r] += __shfl_down(d[r], off, 64);
        }
        if (lane == 0) {
            #pragma unroll
            for (int r = 0; r < 4; ++r) red[rb][wave][r] = d[r];
        }
        asm volatile("s_waitcnt lgkmcnt(0)" ::: "memory");   // red write visible
        __builtin_amdgcn_sched_barrier(0);
        __builtin_amdgcn_s_barrier();                        // NO vmcnt drain
        float pv = (&red[rb][0][0])[lane];                   // lane l -> red[rb][l>>2][l&3]
        pv += __shfl_xor(pv, 4, 64);
        pv += __shfl_xor(pv, 8, 64);
        pv += __shfl_xor(pv, 16, 64);
        pv += __shfl_xor(pv, 32, 64);
        const float inv = 1.f / pv;
        if (t < 4) v[row0 + b * 4 + t] = inv;
        const float vr[4] = {__shfl(inv, 0, 64), __shfl(inv, 1, 64),
                             __shfl(inv, 2, 64), __shfl(inv, 3, 64)};
        #pragma unroll
        for (int r = 0; r < 4; ++r) {
            #pragma unroll
            for (int k = 0; k < 8; ++k)
                acc[k] += vr[r] * (float)e[r][k];
        }
        if (b < CHUNK_ROWS / 4 - 1) {
            #pragma unroll
            for (int r = 0; r < 4; ++r) e[r] = en[r];
        }
    }
    float4* __restrict__ p4 = (float4*)(part + (size_t)blockIdx.x * N);
    p4[2 * t]     = make_float4(acc[0], acc[1], acc[2], acc[3]);
    p4[2 * t + 1] = make_float4(acc[4], acc[5], acc[6], acc[7]);
}

// ---------------------------------------------------------------------------
// u[j] = 1 / sum_c part[c][j].  Grid = 256 blocks; each block 32 cols,
// 8-way split over the 256 chunks.
__global__ __launch_bounds__(256) void col_reduce(const float* __restrict__ part,
                                                  float* __restrict__ u) {
    const int c = threadIdx.x & 31;
    const int seg = threadIdx.x >> 5;            // 0..7
    const int col = blockIdx.x * 32 + c;
    float sum = 0.f;
    #pragma unroll 8
    for (int i = 0; i < CHUNKS / 8; ++i)
        sum += part[(size_t)(seg * (CHUNKS / 8) + i) * N + col];
    __shared__ float smem[8][32];
    smem[seg][c] = sum;
    __syncthreads();
    if (threadIdx.x < 32) {
        float s = 0.f;
        #pragma unroll
        for (int q = 0; q < 8; ++q) s += smem[q][threadIdx.x];
        u[blockIdx.x * 32 + threadIdx.x] = 1.f / s;
    }
}

// ---------------------------------------------------------------------------
// out = exp(s0_ij) * v_i * u_j  (fp32 path; overwrites E/part scratch in d_out)
__global__ __launch_bounds__(256) void final_out(const float* __restrict__ s0,
                                                 const float* __restrict__ v,
                                                 const float* __restrict__ u,
                                                 float* __restrict__ out) {
    const int row = blockIdx.x;
    const float vi = v[row];
    const float4* __restrict__ srow = (const float4*)(s0 + (size_t)row * N);
    const float4* __restrict__ u4 = (const float4*)u;
    float4* __restrict__ orow = (float4*)(out + (size_t)row * N);
    for (int k = threadIdx.x; k < NV4; k += 256) {
        float4 x = srow[k];
        float4 uu = u4[k];
        float4 r;
        r.x = __expf(x.x) * vi * uu.x;
        r.y = __expf(x.y) * vi * uu.y;
        r.z = __expf(x.z) * vi * uu.z;
        r.w = __expf(x.w) * vi * uu.w;
        orow[k] = r;
    }
}

extern "C" void kernel_launch(void* const* d_in, const int* in_sizes, int n_in,
                              void* d_out, int out_size, void* d_ws, size_t ws_size,
                              hipStream_t stream) {
    const float* s0 = (const float*)d_in[0];
    float* out = (float*)d_out;

    _Float16* E = (_Float16*)d_out;                              // 128 MB scratch
    float* part = (float*)((char*)d_out + (size_t)N * N * 2);    // 8 MB at +128 MB
    float* v = (float*)d_ws;                                     // 8192 floats
    float* u = v + N;                                            // 8192 floats

    convert_fused<<<CHUNKS, TB, 0, stream>>>(s0, E, v, part);    // row step #1 (u==1) + col partials
    col_reduce<<<N / 32, 256, 0, stream>>>(part, u);             // col step #1
    for (int it = 1; it < 10; ++it) {
        fused_pass<<<CHUNKS, TB, 0, stream>>>(E, u, v, part);    // row step + col partials
        col_reduce<<<N / 32, 256, 0, stream>>>(part, u);         // col step
    }
    final_out<<<N, 256, 0, stream>>>(s0, v, u, out);
}